// Round 4
// baseline (323.334 us; speedup 1.0000x reference)
//
#include <hip/hip_runtime.h>
#include <math.h>

#define BATCH  2
#define SEQ    2048
#define DMODEL 1024
#define NH     16
#define HD     64
#define NQKV   3072
#define ROWS   (BATCH*SEQ)
#define QSCALE 0.18033688f   // 0.125 * log2(e): QK^T scores land in log2 domain

typedef unsigned short u16;
typedef unsigned int   u32;
typedef __bf16 bf16x8 __attribute__((ext_vector_type(8)));
typedef short  s16x4  __attribute__((ext_vector_type(4)));
typedef float  f32x4  __attribute__((ext_vector_type(4)));

typedef const __attribute__((address_space(1))) void* gptr_t;
typedef __attribute__((address_space(3))) void* lptr_t;

__device__ __forceinline__ void gload16(lptr_t l, const void* g) {
    __builtin_amdgcn_global_load_lds((gptr_t)g, l, 16, 0, 0);
}

__device__ __forceinline__ u16 f2bf(float f) {          // RNE f32->bf16
    unsigned int u = __float_as_uint(f);
    u += 0x7FFFu + ((u >> 16) & 1u);
    return (u16)(u >> 16);
}
__device__ __forceinline__ float bf2f(u16 v) {
    return __uint_as_float(((unsigned int)v) << 16);
}
__device__ __forceinline__ u32 pk2(float lo, float hi) { // pack 2 f32 -> 2 bf16
#if __has_builtin(__builtin_amdgcn_cvt_pk_bf16_f32)
    typedef __bf16 bf16x2 __attribute__((ext_vector_type(2)));
    union { bf16x2 v; u32 u; } cv;
    cv.v = __builtin_amdgcn_cvt_pk_bf16_f32(lo, hi);
    return cv.u;
#else
    return (u32)f2bf(lo) | ((u32)f2bf(hi) << 16);
#endif
}
__device__ __forceinline__ float fexp2(float x) {
#if __has_builtin(__builtin_amdgcn_exp2f)
    return __builtin_amdgcn_exp2f(x);
#else
    return exp2f(x);
#endif
}

// PV micro-op: O^T[16d][16q] += V^T[16d][16key] * P^T[16key][16q], K=16.
#if __has_builtin(__builtin_amdgcn_mfma_f32_16x16x16_bf16)
typedef __bf16 bf16x4 __attribute__((ext_vector_type(4)));
__device__ __forceinline__ f32x4 pv_mfma(u32 v01, u32 v23, u32 p01, u32 p23, f32x4 c) {
    union { uint2 u; bf16x4 v; } a, b;
    a.u = make_uint2(v01, v23); b.u = make_uint2(p01, p23);
    return __builtin_amdgcn_mfma_f32_16x16x16_bf16(a.v, b.v, c, 0, 0, 0);
}
#define PV_K16 1
#elif __has_builtin(__builtin_amdgcn_mfma_f32_16x16x16bf16_1k)
__device__ __forceinline__ f32x4 pv_mfma(u32 v01, u32 v23, u32 p01, u32 p23, f32x4 c) {
    union { uint2 u; s16x4 v; } a, b;
    a.u = make_uint2(v01, v23); b.u = make_uint2(p01, p23);
    return __builtin_amdgcn_mfma_f32_16x16x16bf16_1k(a.v, b.v, c, 0, 0, 0);
}
#define PV_K16 1
#else
#define PV_K16 0   // fallback: zero-padded 16x16x32 with cross-quad shuffles
#endif

// ---------------------------------------------------------------------------
// fused f32 -> bf16 for x, qkv_w, out_w (all counts multiples of 4)
// ---------------------------------------------------------------------------
__global__ void f2bf3_kernel(const float* __restrict__ a, int na,
                             const float* __restrict__ b, int nb,
                             const float* __restrict__ c, int nc,
                             u16* __restrict__ oa, u16* __restrict__ ob,
                             u16* __restrict__ oc)
{
    int i = (blockIdx.x * 256 + threadIdx.x) * 4;
    const float* s; u16* d; int base;
    if (i < na)                { s = a; d = oa; base = i; }
    else if (i < na + nb)      { s = b; d = ob; base = i - na; }
    else if (i < na + nb + nc) { s = c; d = oc; base = i - na - nb; }
    else return;
    float4 v = *(const float4*)(s + base);
    u16 o[4] = { f2bf(v.x), f2bf(v.y), f2bf(v.z), f2bf(v.w) };
    *(uint2*)(d + base) = *(const uint2*)o;
}

// ---------------------------------------------------------------------------
// wtab[h][d] = exp(-max(p,.01)*log1p(max(a,.01)*d))  (multiplicative bias)
// ---------------------------------------------------------------------------
__global__ void wtab_kernel(const float* __restrict__ bias_p,
                            const float* __restrict__ bias_a,
                            float* __restrict__ wtab)
{
    int idx = blockIdx.x * 256 + threadIdx.x;
    int h = idx >> 11;
    int d = idx & (SEQ - 1);
    float p = fmaxf(bias_p[h], 0.01f);
    float a = fmaxf(bias_a[h], 0.01f);
    wtab[idx] = __expf(-p * log1pf(a * (float)d));
}

// cs_tab[(s*32+d)*2] = cos(s*freqs[d]), +1 = sin
__global__ void rope_table_kernel(const float* __restrict__ freqs, float* __restrict__ tab)
{
    int idx = blockIdx.x * 256 + threadIdx.x;   // SEQ*32
    int s = idx >> 5, d = idx & 31;
    float sn, cs;
    sincosf((float)s * freqs[d], &sn, &cs);
    tab[idx * 2]     = cs;
    tab[idx * 2 + 1] = sn;
}

// ---------------------------------------------------------------------------
// bf16 NT GEMM, m97-style: 128x128 tile, BK=32, global_load_lds staging with
// XOR chunk swizzle (chunk' = chunk ^ (row&3), chunk = 8 u16 = 16B).
// ---------------------------------------------------------------------------
template<bool BF16OUT>
__global__ __launch_bounds__(256) void gemm_bf16(
    const u16* __restrict__ A, const u16* __restrict__ B,
    void* __restrict__ Cout, int M, int N, int K)
{
    __shared__ __align__(16) u16 As[128][32];
    __shared__ __align__(16) u16 Bs[128][32];
    const int tid  = threadIdx.x;
    const int wave = tid >> 6, lane = tid & 63;
    const int quad = lane >> 4, l16 = lane & 15;
    const int wrow = (wave >> 1) * 64, wcol = (wave & 1) * 64;
    const int bm = blockIdx.x * 128, bn = blockIdx.y * 128;

    const int srow = lane >> 2;                       // 0..15
    const int scol = ((lane & 3) ^ (srow & 3)) * 8;   // swizzled chunk (u16)
    const int fsw = (quad ^ (l16 & 3)) * 8;           // frag read swizzle

    f32x4 acc[4][4];
#pragma unroll
    for (int i = 0; i < 4; ++i)
#pragma unroll
        for (int j = 0; j < 4; ++j) acc[i][j] = (f32x4){0.f,0.f,0.f,0.f};

    const u16* Ag0 = A + (size_t)(bm + wave*32 + srow)      * K + scol;
    const u16* Ag1 = A + (size_t)(bm + wave*32 + 16 + srow) * K + scol;
    const u16* Bg0 = B + (size_t)(bn + wave*32 + srow)      * K + scol;
    const u16* Bg1 = B + (size_t)(bn + wave*32 + 16 + srow) * K + scol;

    for (int k0 = 0; k0 < K; k0 += 32) {
        __syncthreads();
        gload16((lptr_t)&As[wave*32][0],      Ag0 + k0);
        gload16((lptr_t)&As[wave*32 + 16][0], Ag1 + k0);
        gload16((lptr_t)&Bs[wave*32][0],      Bg0 + k0);
        gload16((lptr_t)&Bs[wave*32 + 16][0], Bg1 + k0);
        __syncthreads();
        bf16x8 af[4], bfr[4];
#pragma unroll
        for (int i = 0; i < 4; ++i)
            af[i] = *(const bf16x8*)&As[wrow + i*16 + l16][fsw];
#pragma unroll
        for (int j = 0; j < 4; ++j)
            bfr[j] = *(const bf16x8*)&Bs[wcol + j*16 + l16][fsw];
#pragma unroll
        for (int i = 0; i < 4; ++i)
#pragma unroll
            for (int j = 0; j < 4; ++j)
                acc[i][j] = __builtin_amdgcn_mfma_f32_16x16x32_bf16(af[i], bfr[j], acc[i][j], 0, 0, 0);
    }

#pragma unroll
    for (int i = 0; i < 4; ++i)
#pragma unroll
        for (int j = 0; j < 4; ++j) {
            int col = bn + wcol + j*16 + l16;
#pragma unroll
            for (int r = 0; r < 4; ++r) {
                int row = bm + wrow + i*16 + quad*4 + r;
                if (BF16OUT) ((u16*)Cout)[(size_t)row * N + col] = f2bf(acc[i][j][r]);
                else         ((float*)Cout)[(size_t)row * N + col] = acc[i][j][r];
            }
        }
}

// ---------------------------------------------------------------------------
// RoPE (table-based) + layout conversion, tiled. Block = (64 s-rows, h, b).
// Writes Qb[b][h][s][d] (scaled QSCALE), Kb[b][h][s][d], Vt[b][h][d][s].
// ---------------------------------------------------------------------------
__global__ __launch_bounds__(256) void qkv_convert(
    const u16* __restrict__ qkv_bf, const float* __restrict__ cs_tab,
    u16* __restrict__ Qb, u16* __restrict__ Kb, u16* __restrict__ Vt)
{
    __shared__ __align__(16) u16 Vtile[64][72];
    const int tid = threadIdx.x;
    const int r = tid >> 2, c = tid & 3;
    const int s0 = blockIdx.x * 64, h = blockIdx.y, b = blockIdx.z;
    const int s = s0 + r;
    const u16* src = qkv_bf + (size_t)(b * SEQ + s) * NQKV + h * HD;
    const size_t hb = (size_t)(b * NH + h) * SEQ * HD;

    *(uint4*)&Vtile[r][c*16]     = *(const uint4*)(src + 2*NH*HD + c*16);
    *(uint4*)&Vtile[r][c*16 + 8] = *(const uint4*)(src + 2*NH*HD + c*16 + 8);

    {
        const u16* m = src + ((c < 2) ? 0 : NH*HD);
        const int d1 = (c & 1) * 16;
        u16 x1[16], x2[16];
        *(uint4*)&x1[0] = *(const uint4*)(m + d1);
        *(uint4*)&x1[8] = *(const uint4*)(m + d1 + 8);
        *(uint4*)&x2[0] = *(const uint4*)(m + d1 + 32);
        *(uint4*)&x2[8] = *(const uint4*)(m + d1 + 40);
        const float* ct = cs_tab + ((size_t)s * 32 + d1) * 2;
        const float sc = (c < 2) ? QSCALE : 1.0f;
        u16 y1[16], y2[16];
#pragma unroll
        for (int u = 0; u < 16; ++u) {
            float cs = ct[u*2], sn = ct[u*2 + 1];
            float a = bf2f(x1[u]), bq = bf2f(x2[u]);
            y1[u] = f2bf((a * cs - bq * sn) * sc);
            y2[u] = f2bf((a * sn + bq * cs) * sc);
        }
        u16* dst = ((c < 2) ? Qb : Kb) + hb + (size_t)s * HD + d1;
        *(uint4*)(dst)      = *(const uint4*)&y1[0];
        *(uint4*)(dst + 8)  = *(const uint4*)&y1[8];
        *(uint4*)(dst + 32) = *(const uint4*)&y2[0];
        *(uint4*)(dst + 40) = *(const uint4*)&y2[8];
    }
    __syncthreads();

    u16 vv[16];
#pragma unroll
    for (int u = 0; u < 16; ++u) vv[u] = Vtile[c*16 + u][r];
    u16* dst = Vt + hb + (size_t)r * SEQ + s0 + c*16;
    *(uint4*)(dst)     = *(const uint4*)&vv[0];
    *(uint4*)(dst + 8) = *(const uint4*)&vv[8];
}

// ---------------------------------------------------------------------------
// MFMA flash attention v2: key-partitioned waves, in-register P.
// Block = (64 q, h, b); wave w owns keys w*16..w*16+15 of each 64-key tile.
// S^T = K*Q^T (operand swap) puts scores in exactly the B-operand layout of a
// K=16 MFMA over keys -> P stays in VGPRs. O^T = V^T * P^T accumulated per
// wave; cross-wave reduction via LDS atomics once per block.
// Bias is multiplicative: w = exp(kb) gathered from a 128-entry signed window
// of bf16 pairs (2 b32 reads per 16q-block, no abs/dist arithmetic).
// ---------------------------------------------------------------------------
__global__ __launch_bounds__(256) void attn_mfma(
    const u16* __restrict__ Qb, const u16* __restrict__ Kb,
    const u16* __restrict__ Vt, const float* __restrict__ wtab,
    u16* __restrict__ attn_bf)
{
    __shared__ __align__(16) char smem[17408];
    u16* Ks  = (u16*)smem;              // [64][64] keys x d, chunk-swizzled
    u16* Vs  = (u16*)(smem + 8192);     // [64][64] d x keys, chunk-swizzled
    u32* ws2 = (u32*)(smem + 16384);    // [128] packed bf16 pairs {w[m],w[m+1]}

    const int tid = threadIdx.x;
    const int wave = tid >> 6, lane = tid & 63;
    const int quad = lane >> 4, l16 = lane & 15;
    const int q0 = blockIdx.x * 64, h = blockIdx.y, b = blockIdx.z;

    const u16* Qh = Qb + (size_t)(b * NH + h) * SEQ * HD;
    const u16* Kh = Kb + (size_t)(b * NH + h) * SEQ * HD;
    const u16* Vh = Vt + (size_t)(b * NH + h) * HD * SEQ;
    const float* wh = wtab + h * SEQ;

    // Q fragments: all 64 q rows held per wave (B-operand of S^T)
    bf16x8 qf0[4], qf1[4];
#pragma unroll
    for (int qj = 0; qj < 4; ++qj) {
        const u16* qr = Qh + (size_t)(q0 + qj*16 + l16) * HD + quad * 8;
        qf0[qj] = *(const bf16x8*)qr;
        qf1[qj] = *(const bf16x8*)(qr + 32);
    }

    // staging lane map: 8 rows x 8 chunks per issue, chunk' = chunk ^ (row&7)
    const int srow = lane >> 3;
    const int scol = ((lane & 7) ^ srow) * 8;
    const u16* Kg0 = Kh + (size_t)(wave*16 + srow)     * HD + scol;
    const u16* Kg1 = Kh + (size_t)(wave*16 + 8 + srow) * HD + scol;
    const u16* Vg0 = Vh + (size_t)(wave*16 + srow)     * SEQ + scol;
    const u16* Vg1 = Vh + (size_t)(wave*16 + 8 + srow) * SEQ + scol;

    const int sw  = (quad ^ (l16 & 7)) * 8;            // kf chunk offset (u16)
    const int mb0 = 63 + l16 - wave*16 - quad*4 - 3;   // w-window base (>=0)

    float l_p[4] = {0.f, 0.f, 0.f, 0.f};
    f32x4 o[4][4];
#pragma unroll
    for (int di = 0; di < 4; ++di)
#pragma unroll
        for (int qj = 0; qj < 4; ++qj) o[di][qj] = (f32x4){0.f,0.f,0.f,0.f};

    for (int kt = 0; kt < SEQ / 64; ++kt) {
        const int k0 = kt * 64;
        __syncthreads();                   // prior tile's frag reads done
        gload16((lptr_t)&Ks[(wave*16)*64],     Kg0 + (size_t)k0 * HD);
        gload16((lptr_t)&Ks[(wave*16 + 8)*64], Kg1 + (size_t)k0 * HD);
        gload16((lptr_t)&Vs[(wave*16)*64],     Vg0 + k0);
        gload16((lptr_t)&Vs[(wave*16 + 8)*64], Vg1 + k0);
        if (tid < 128) {                   // signed bias window, bf16 pairs
            int i0 = (q0 - k0 - 63) + tid;
            int a0 = i0 < 0 ? -i0 : i0;  if (a0 > SEQ-1) a0 = SEQ-1;
            int i1 = i0 + 1;
            int a1 = i1 < 0 ? -i1 : i1;  if (a1 > SEQ-1) a1 = SEQ-1;
            ws2[tid] = pk2(wh[a0], wh[a1]);
        }
        __syncthreads();

        // ---- S^T = K * Q^T over this wave's 16 keys ----
        bf16x8 kf0 = *(const bf16x8*)&Ks[(wave*16 + l16)*64 + sw];
        bf16x8 kf1 = *(const bf16x8*)&Ks[(wave*16 + l16)*64 + (sw ^ 32)];
        u32 pp[4][2];
#pragma unroll
        for (int qj = 0; qj < 4; ++qj) {
            f32x4 z = (f32x4){0.f,0.f,0.f,0.f};
            z = __builtin_amdgcn_mfma_f32_16x16x32_bf16(kf0, qf0[qj], z, 0, 0, 0);
            z = __builtin_amdgcn_mfma_f32_16x16x32_bf16(kf1, qf1[qj], z, 0, 0, 0);
            const int mbase = mb0 + qj*16;
            u32 pA = ws2[mbase], pB = ws2[mbase + 2];
            float w3 = __uint_as_float(pA << 16);
            float w2 = __uint_as_float(pA & 0xffff0000u);
            float w1 = __uint_as_float(pB << 16);
            float w0 = __uint_as_float(pB & 0xffff0000u);
            float e0 = fexp2(z[0]) * w0, e1 = fexp2(z[1]) * w1;
            float e2 = fexp2(z[2]) * w2, e3 = fexp2(z[3]) * w3;
            l_p[qj] += (e0 + e1) + (e2 + e3);
            pp[qj][0] = pk2(e0, e1);
            pp[qj][1] = pk2(e2, e3);
        }

        // ---- O^T += V^T * P^T (K=16 over this wave's keys) ----
#if PV_K16
#pragma unroll
        for (int di = 0; di < 4; ++di) {
            const int row = di*16 + l16;
            const int c   = 2*wave + (quad >> 1);
            const int off = ((c ^ (row & 7)) * 8) + (quad & 1) * 4;
            uint2 vv = *(const uint2*)&Vs[row*64 + off];
#pragma unroll
            for (int qj = 0; qj < 4; ++qj)
                o[di][qj] = pv_mfma(vv.x, vv.y, pp[qj][0], pp[qj][1], o[di][qj]);
        }
#else
        // zero-padded 16x16x32 fallback: keys in k-slots 0..15, quads>=2 zero
#pragma unroll
        for (int di = 0; di < 4; ++di) {
            const int row = di*16 + l16;
            union { uint4 u; bf16x8 v; } va;
            if (quad < 2) {
                const int c = 2*wave + quad;
                va.u = *(const uint4*)&Vs[row*64 + ((c ^ (row & 7)) * 8)];
            } else va.u = make_uint4(0,0,0,0);
#pragma unroll
            for (int qj = 0; qj < 4; ++qj) {
                u32 s1a = __shfl_down(pp[qj][0], 16), s1b = __shfl_down(pp[qj][1], 16);
                u32 s2a = __shfl_down(pp[qj][0], 32), s2b = __shfl_down(pp[qj][1], 32);
                union { uint4 u; bf16x8 v; } pb;
                if (quad == 0)      pb.u = make_uint4(pp[qj][0], pp[qj][1], s1a, s1b);
                else if (quad == 1) pb.u = make_uint4(s1a, s1b, s2a, s2b);
                else                pb.u = make_uint4(0,0,0,0);
                o[di][qj] = __builtin_amdgcn_mfma_f32_16x16x32_bf16(va.v, pb.v, o[di][qj], 0, 0, 0);
            }
        }
#endif
    }

    // ---- epilogue: cross-wave reduce O^T and l via LDS, normalize, store ----
    __syncthreads();
    float* Red = (float*)smem;             // [64 d][66] + ls[64]
    float* ls  = Red + 64*66;
    for (int i = tid; i < 64*66 + 64; i += 256) Red[i] = 0.f;
    __syncthreads();
#pragma unroll
    for (int qj = 0; qj < 4; ++qj)
        atomicAdd(&ls[qj*16 + l16], l_p[qj]);
#pragma unroll
    for (int di = 0; di < 4; ++di)
#pragma unroll
        for (int qj = 0; qj < 4; ++qj)
#pragma unroll
            for (int r = 0; r < 4; ++r)
                atomicAdd(&Red[(di*16 + quad*4 + r)*66 + qj*16 + l16], o[di][qj][r]);
    __syncthreads();

    {
        const int q = tid >> 2, dc = (tid & 3) * 16;
        float inv = 1.0f / ls[q];
        u16 ov[16];
#pragma unroll
        for (int u = 0; u < 16; ++u)
            ov[u] = f2bf(Red[(dc + u)*66 + q] * inv);
        u16* dst = attn_bf + (size_t)(b * SEQ + q0 + q) * DMODEL + h * HD + dc;
        *(uint4*)(dst)     = *(const uint4*)&ov[0];
        *(uint4*)(dst + 8) = *(const uint4*)&ov[8];
    }
}

// ---------------------------------------------------------------------------
extern "C" void kernel_launch(void* const* d_in, const int* in_sizes, int n_in,
                              void* d_out, int out_size, void* d_ws, size_t ws_size,
                              hipStream_t stream)
{
    (void)in_sizes; (void)n_in; (void)out_size; (void)ws_size;
    const float* x      = (const float*)d_in[0];
    const float* qkv_w  = (const float*)d_in[1];
    const float* out_w  = (const float*)d_in[2];
    const float* bias_p = (const float*)d_in[3];
    const float* bias_a = (const float*)d_in[4];
    const float* freqs  = (const float*)d_in[5];
    float* out = (float*)d_out;

    // ws layout (bytes):
    //   [0, 24M)      qkv_bf [4096][3072] bf16   (attn_bf aliases [0,8M))
    //   [24M, 32M)    x_bf   [4096][1024] bf16   (Qb aliases after gemm1)
    //   [32M, 38M)    w1_bf  [3072][1024] bf16
    //   [38M, 40M)    w2_bf  [1024][1024] bf16
    //   [40M, 48M)    Kb     [2][16][2048][64] bf16
    //   [48M, 56M)    Vt     [2][16][64][2048] bf16
    //   [56M, +128K)  wtab   [16][2048] f32 (exp of bias)
    //   [+128K,+640K) cs_tab [2048][32][2] f32
    char* ws = (char*)d_ws;
    u16*   qkv_bf  = (u16*)ws;
    u16*   attn_bf = (u16*)ws;
    u16*   x_bf    = (u16*)(ws + 25165824);
    u16*   Qb      = x_bf;
    u16*   w1_bf   = (u16*)(ws + 33554432);
    u16*   w2_bf   = (u16*)(ws + 39845888);
    u16*   Kb      = (u16*)(ws + 41943040);
    u16*   Vt      = (u16*)(ws + 50331648);
    float* wtab    = (float*)(ws + 58720256);
    float* cs_tab  = (float*)(ws + 58720256 + 131072);

    const int na = ROWS*DMODEL, nb = NQKV*DMODEL, nc = DMODEL*DMODEL;
    f2bf3_kernel<<<dim3((na+nb+nc)/1024), 256, 0, stream>>>(x, na, qkv_w, nb, out_w, nc,
                                                            x_bf, w1_bf, w2_bf);
    rope_table_kernel<<<dim3(SEQ*32/256), 256, 0, stream>>>(freqs, cs_tab);
    wtab_kernel<<<dim3(NH*SEQ/256), 256, 0, stream>>>(bias_p, bias_a, wtab);

    gemm_bf16<true><<<dim3(ROWS/128, NQKV/128), 256, 0, stream>>>(x_bf, w1_bf, qkv_bf, ROWS, NQKV, DMODEL);
    qkv_convert<<<dim3(SEQ/64, NH, BATCH), 256, 0, stream>>>(qkv_bf, cs_tab, Qb, Kb, Vt);
    attn_mfma<<<dim3(SEQ/64, NH, BATCH), 256, 0, stream>>>(Qb, Kb, Vt, wtab, attn_bf);
    gemm_bf16<false><<<dim3(ROWS/128, DMODEL/128), 256, 0, stream>>>(attn_bf, w2_bf, out, ROWS, DMODEL, DMODEL);
}

// Round 5
// 234.119 us; speedup vs baseline: 1.3811x; 1.3811x over previous
//
#include <hip/hip_runtime.h>
#include <math.h>

#define BATCH  2
#define SEQ    2048
#define DMODEL 1024
#define NH     16
#define HD     64
#define NQKV   3072
#define ROWS   (BATCH*SEQ)
#define QSCALE 0.18033688f   // 0.125 * log2(e): QK^T scores land in log2 domain

typedef unsigned short u16;
typedef unsigned int   u32;
typedef __bf16 bf16x8 __attribute__((ext_vector_type(8)));
typedef float  f32x4  __attribute__((ext_vector_type(4)));

typedef const __attribute__((address_space(1))) void* gptr_t;
typedef __attribute__((address_space(3))) void* lptr_t;

__device__ __forceinline__ void gload16(lptr_t l, const void* g) {
    __builtin_amdgcn_global_load_lds((gptr_t)g, l, 16, 0, 0);
}

__device__ __forceinline__ u16 f2bf(float f) {          // RNE f32->bf16
    unsigned int u = __float_as_uint(f);
    u += 0x7FFFu + ((u >> 16) & 1u);
    return (u16)(u >> 16);
}
__device__ __forceinline__ float bf2f(u16 v) {
    return __uint_as_float(((unsigned int)v) << 16);
}
__device__ __forceinline__ u32 pk2(float lo, float hi) { // pack 2 f32 -> 2 bf16
#if __has_builtin(__builtin_amdgcn_cvt_pk_bf16_f32)
    typedef __bf16 bf16x2 __attribute__((ext_vector_type(2)));
    union { bf16x2 v; u32 u; } cv;
    cv.v = __builtin_amdgcn_cvt_pk_bf16_f32(lo, hi);
    return cv.u;
#else
    return (u32)f2bf(lo) | ((u32)f2bf(hi) << 16);
#endif
}
__device__ __forceinline__ float fexp2(float x) {
#if __has_builtin(__builtin_amdgcn_exp2f)
    return __builtin_amdgcn_exp2f(x);
#else
    return exp2f(x);
#endif
}

// ---------------------------------------------------------------------------
// fused f32 -> bf16 for x, qkv_w, out_w
// ---------------------------------------------------------------------------
__global__ void f2bf3_kernel(const float* __restrict__ a, int na,
                             const float* __restrict__ b, int nb,
                             const float* __restrict__ c, int nc,
                             u16* __restrict__ oa, u16* __restrict__ ob,
                             u16* __restrict__ oc)
{
    int i = (blockIdx.x * 256 + threadIdx.x) * 4;
    const float* s; u16* d; int base;
    if (i < na)                { s = a; d = oa; base = i; }
    else if (i < na + nb)      { s = b; d = ob; base = i - na; }
    else if (i < na + nb + nc) { s = c; d = oc; base = i - na - nb; }
    else return;
    float4 v = *(const float4*)(s + base);
    u16 o[4] = { f2bf(v.x), f2bf(v.y), f2bf(v.z), f2bf(v.w) };
    *(uint2*)(d + base) = *(const uint2*)o;
}

// ---------------------------------------------------------------------------
// wtab[h][d] = exp(-max(p,.01)*log1p(max(a,.01)*d))  (multiplicative bias)
// ---------------------------------------------------------------------------
__global__ void wtab_kernel(const float* __restrict__ bias_p,
                            const float* __restrict__ bias_a,
                            float* __restrict__ wtab)
{
    int idx = blockIdx.x * 256 + threadIdx.x;
    int h = idx >> 11;
    int d = idx & (SEQ - 1);
    float p = fmaxf(bias_p[h], 0.01f);
    float a = fmaxf(bias_a[h], 0.01f);
    wtab[idx] = __expf(-p * log1pf(a * (float)d));
}

// cs_tab[(s*32+d)*2] = cos(s*freqs[d]), +1 = sin
__global__ void rope_table_kernel(const float* __restrict__ freqs, float* __restrict__ tab)
{
    int idx = blockIdx.x * 256 + threadIdx.x;   // SEQ*32
    int s = idx >> 5, d = idx & 31;
    float sn, cs;
    sincosf((float)s * freqs[d], &sn, &cs);
    tab[idx * 2]     = cs;
    tab[idx * 2 + 1] = sn;
}

// ---------------------------------------------------------------------------
// bf16 NT GEMM, m97-style: 128x128 tile, BK=32, global_load_lds staging with
// XOR chunk swizzle (chunk' = chunk ^ (row&3), chunk = 8 u16 = 16B).
// ---------------------------------------------------------------------------
template<bool BF16OUT>
__global__ __launch_bounds__(256) void gemm_bf16(
    const u16* __restrict__ A, const u16* __restrict__ B,
    void* __restrict__ Cout, int M, int N, int K)
{
    __shared__ __align__(16) u16 As[128][32];
    __shared__ __align__(16) u16 Bs[128][32];
    const int tid  = threadIdx.x;
    const int wave = tid >> 6, lane = tid & 63;
    const int quad = lane >> 4, l16 = lane & 15;
    const int wrow = (wave >> 1) * 64, wcol = (wave & 1) * 64;
    const int bm = blockIdx.x * 128, bn = blockIdx.y * 128;

    const int srow = lane >> 2;                       // 0..15
    const int scol = ((lane & 3) ^ (srow & 3)) * 8;   // swizzled chunk (u16)
    const int fsw = (quad ^ (l16 & 3)) * 8;           // frag read swizzle

    f32x4 acc[4][4];
#pragma unroll
    for (int i = 0; i < 4; ++i)
#pragma unroll
        for (int j = 0; j < 4; ++j) acc[i][j] = (f32x4){0.f,0.f,0.f,0.f};

    const u16* Ag0 = A + (size_t)(bm + wave*32 + srow)      * K + scol;
    const u16* Ag1 = A + (size_t)(bm + wave*32 + 16 + srow) * K + scol;
    const u16* Bg0 = B + (size_t)(bn + wave*32 + srow)      * K + scol;
    const u16* Bg1 = B + (size_t)(bn + wave*32 + 16 + srow) * K + scol;

    for (int k0 = 0; k0 < K; k0 += 32) {
        __syncthreads();
        gload16((lptr_t)&As[wave*32][0],      Ag0 + k0);
        gload16((lptr_t)&As[wave*32 + 16][0], Ag1 + k0);
        gload16((lptr_t)&Bs[wave*32][0],      Bg0 + k0);
        gload16((lptr_t)&Bs[wave*32 + 16][0], Bg1 + k0);
        __syncthreads();
        bf16x8 af[4], bfr[4];
#pragma unroll
        for (int i = 0; i < 4; ++i)
            af[i] = *(const bf16x8*)&As[wrow + i*16 + l16][fsw];
#pragma unroll
        for (int j = 0; j < 4; ++j)
            bfr[j] = *(const bf16x8*)&Bs[wcol + j*16 + l16][fsw];
#pragma unroll
        for (int i = 0; i < 4; ++i)
#pragma unroll
            for (int j = 0; j < 4; ++j)
                acc[i][j] = __builtin_amdgcn_mfma_f32_16x16x32_bf16(af[i], bfr[j], acc[i][j], 0, 0, 0);
    }

#pragma unroll
    for (int i = 0; i < 4; ++i)
#pragma unroll
        for (int j = 0; j < 4; ++j) {
            int col = bn + wcol + j*16 + l16;
#pragma unroll
            for (int r = 0; r < 4; ++r) {
                int row = bm + wrow + i*16 + quad*4 + r;
                if (BF16OUT) ((u16*)Cout)[(size_t)row * N + col] = f2bf(acc[i][j][r]);
                else         ((float*)Cout)[(size_t)row * N + col] = acc[i][j][r];
            }
        }
}

// ---------------------------------------------------------------------------
// RoPE (table-based) + layout conversion, tiled. Block = (64 s-rows, h, b).
// Writes Qb[b][h][s][d] (scaled QSCALE), Kb[b][h][s][d], Vt[b][h][d][s].
// ---------------------------------------------------------------------------
__global__ __launch_bounds__(256) void qkv_convert(
    const u16* __restrict__ qkv_bf, const float* __restrict__ cs_tab,
    u16* __restrict__ Qb, u16* __restrict__ Kb, u16* __restrict__ Vt)
{
    __shared__ __align__(16) u16 Vtile[64][72];
    const int tid = threadIdx.x;
    const int r = tid >> 2, c = tid & 3;
    const int s0 = blockIdx.x * 64, h = blockIdx.y, b = blockIdx.z;
    const int s = s0 + r;
    const u16* src = qkv_bf + (size_t)(b * SEQ + s) * NQKV + h * HD;
    const size_t hb = (size_t)(b * NH + h) * SEQ * HD;

    *(uint4*)&Vtile[r][c*16]     = *(const uint4*)(src + 2*NH*HD + c*16);
    *(uint4*)&Vtile[r][c*16 + 8] = *(const uint4*)(src + 2*NH*HD + c*16 + 8);

    {
        const u16* m = src + ((c < 2) ? 0 : NH*HD);
        const int d1 = (c & 1) * 16;
        u16 x1[16], x2[16];
        *(uint4*)&x1[0] = *(const uint4*)(m + d1);
        *(uint4*)&x1[8] = *(const uint4*)(m + d1 + 8);
        *(uint4*)&x2[0] = *(const uint4*)(m + d1 + 32);
        *(uint4*)&x2[8] = *(const uint4*)(m + d1 + 40);
        const float* ct = cs_tab + ((size_t)s * 32 + d1) * 2;
        const float sc = (c < 2) ? QSCALE : 1.0f;
        u16 y1[16], y2[16];
#pragma unroll
        for (int u = 0; u < 16; ++u) {
            float cs = ct[u*2], sn = ct[u*2 + 1];
            float a = bf2f(x1[u]), bq = bf2f(x2[u]);
            y1[u] = f2bf((a * cs - bq * sn) * sc);
            y2[u] = f2bf((a * sn + bq * cs) * sc);
        }
        u16* dst = ((c < 2) ? Qb : Kb) + hb + (size_t)s * HD + d1;
        *(uint4*)(dst)      = *(const uint4*)&y1[0];
        *(uint4*)(dst + 8)  = *(const uint4*)&y1[8];
        *(uint4*)(dst + 32) = *(const uint4*)&y2[0];
        *(uint4*)(dst + 40) = *(const uint4*)&y2[8];
    }
    __syncthreads();

    u16 vv[16];
#pragma unroll
    for (int u = 0; u < 16; ++u) vv[u] = Vtile[c*16 + u][r];
    u16* dst = Vt + hb + (size_t)r * SEQ + s0 + c*16;
    *(uint4*)(dst)     = *(const uint4*)&vv[0];
    *(uint4*)(dst + 8) = *(const uint4*)&vv[8];
}

// ---------------------------------------------------------------------------
// MFMA flash attention v3 (R3 skeleton + swapped-score softmax).
// Block = (64 q, h, b), 4 waves. Scores computed as S^T = K*Q^T: wave w's
// MFMA A-operand is its own 16 keys, B-operand is all 64 q rows (regs).
// C-layout then gives each lane 4 CONSECUTIVE keys for one q -> packed
// bf16 pairs, single ds_write_b64 per qj (vs 16 ds_write_b16 in R3), and the
// multiplicative bias window (ws2 pairs, consecutive-lane = conflict-free)
// replaces 16 scalar gathers + dist VALU. exp in log2 domain (QSCALE).
// PV identical to R3: wave w reads P rows w*16.. as A-operand, Vs[d][key]
// as B-operand, 8 MFMA 16x16x32. One extra barrier/tile (P is cross-wave).
// ---------------------------------------------------------------------------
__global__ __launch_bounds__(256) void attn_mfma(
    const u16* __restrict__ Qb, const u16* __restrict__ Kb,
    const u16* __restrict__ Vt, const float* __restrict__ wtab,
    u16* __restrict__ attn_bf)
{
    __shared__ __align__(16) u16 Ks[64*64];    // [key][d], chunk-swizzled
    __shared__ __align__(16) u16 Vs[64*64];    // [d][key], chunk-swizzled
    __shared__ __align__(16) u16 Ps[64][72];   // [q][key], padded
    __shared__ u32 ws2[128];                   // packed {w[m], w[m+1]}
    __shared__ float lred[4][64];
    __shared__ float linv[64];

    const int tid = threadIdx.x;
    const int wave = tid >> 6, lane = tid & 63;
    const int quad = lane >> 4, l16 = lane & 15;
    const int q0 = blockIdx.x * 64, h = blockIdx.y, b = blockIdx.z;

    const u16* Qh = Qb + (size_t)(b * NH + h) * SEQ * HD;
    const u16* Kh = Kb + (size_t)(b * NH + h) * SEQ * HD;
    const u16* Vh = Vt + (size_t)(b * NH + h) * HD * SEQ;
    const float* wh = wtab + h * SEQ;

    // Q fragments (B-operand of S^T): all 64 q rows per wave, in registers
    bf16x8 qf0[4], qf1[4];
#pragma unroll
    for (int qj = 0; qj < 4; ++qj) {
        const u16* qr = Qh + (size_t)(q0 + qj*16 + l16) * HD + quad * 8;
        qf0[qj] = *(const bf16x8*)qr;
        qf1[qj] = *(const bf16x8*)(qr + 32);
    }

    // staging lane map: 8 rows x 8 chunks per issue, chunk' = chunk ^ (row&7)
    const int srow = lane >> 3;
    const int scol = ((lane & 7) ^ srow) * 8;
    const u16* Kg0 = Kh + (size_t)(wave*16 + srow)     * HD + scol;
    const u16* Kg1 = Kh + (size_t)(wave*16 + 8 + srow) * HD + scol;
    const u16* Vg0 = Vh + (size_t)(wave*16 + srow)     * SEQ + scol;
    const u16* Vg1 = Vh + (size_t)(wave*16 + 8 + srow) * SEQ + scol;

    const int sw  = (quad ^ (l16 & 7)) * 8;            // frag chunk offset
    const int mb0 = 63 + l16 - wave*16 - quad*4 - 3;   // w-window base (>=0)

    float l_p[4] = {0.f, 0.f, 0.f, 0.f};
    f32x4 o[4];
#pragma unroll
    for (int j = 0; j < 4; ++j) o[j] = (f32x4){0.f,0.f,0.f,0.f};

    for (int kt = 0; kt < SEQ / 64; ++kt) {
        const int k0 = kt * 64;
        __syncthreads();                   // prior tile's Ks/Vs/Ps/ws2 reads done
        gload16((lptr_t)&Ks[(wave*16)*64],     Kg0 + (size_t)k0 * HD);
        gload16((lptr_t)&Ks[(wave*16 + 8)*64], Kg1 + (size_t)k0 * HD);
        gload16((lptr_t)&Vs[(wave*16)*64],     Vg0 + k0);
        gload16((lptr_t)&Vs[(wave*16 + 8)*64], Vg1 + k0);
        if (tid < 128) {                   // signed bias window, bf16 pairs
            int i0 = (q0 - k0 - 63) + tid;
            int a0 = i0 < 0 ? -i0 : i0;  if (a0 > SEQ-1) a0 = SEQ-1;
            int i1 = i0 + 1;
            int a1 = i1 < 0 ? -i1 : i1;  if (a1 > SEQ-1) a1 = SEQ-1;
            ws2[tid] = pk2(wh[a0], wh[a1]);
        }
        __syncthreads();

        // ---- S^T = K * Q^T for this wave's 16 keys; softmax; P write ----
        bf16x8 kf0 = *(const bf16x8*)&Ks[(wave*16 + l16)*64 + sw];
        bf16x8 kf1 = *(const bf16x8*)&Ks[(wave*16 + l16)*64 + (sw ^ 32)];
#pragma unroll
        for (int qj = 0; qj < 4; ++qj) {
            f32x4 z = (f32x4){0.f,0.f,0.f,0.f};
            z = __builtin_amdgcn_mfma_f32_16x16x32_bf16(kf0, qf0[qj], z, 0, 0, 0);
            z = __builtin_amdgcn_mfma_f32_16x16x32_bf16(kf1, qf1[qj], z, 0, 0, 0);
            const int mbase = mb0 + qj*16;
            u32 pA = ws2[mbase], pB = ws2[mbase + 2];
            float w3 = __uint_as_float(pA << 16);
            float w2 = __uint_as_float(pA & 0xffff0000u);
            float w1 = __uint_as_float(pB << 16);
            float w0 = __uint_as_float(pB & 0xffff0000u);
            float e0 = fexp2(z[0]) * w0, e1 = fexp2(z[1]) * w1;
            float e2 = fexp2(z[2]) * w2, e3 = fexp2(z[3]) * w3;
            l_p[qj] += (e0 + e1) + (e2 + e3);
            // 4 consecutive keys (wave*16+quad*4..+3) for q = qj*16+l16
            *(uint2*)&Ps[qj*16 + l16][wave*16 + quad*4] =
                make_uint2(pk2(e0, e1), pk2(e2, e3));
        }
        __syncthreads();                   // P visible to all waves

        // ---- PV: O[q=wave rows][d] += P * V  (identical to R3) ----
        bf16x8 pf0 = *(const bf16x8*)&Ps[wave*16 + l16][quad*8];
        bf16x8 pf1 = *(const bf16x8*)&Ps[wave*16 + l16][32 + quad*8];
#pragma unroll
        for (int j = 0; j < 4; ++j) {
            bf16x8 vf0 = *(const bf16x8*)&Vs[(j*16 + l16)*64 + sw];
            bf16x8 vf1 = *(const bf16x8*)&Vs[(j*16 + l16)*64 + (sw ^ 32)];
            o[j] = __builtin_amdgcn_mfma_f32_16x16x32_bf16(pf0, vf0, o[j], 0, 0, 0);
            o[j] = __builtin_amdgcn_mfma_f32_16x16x32_bf16(pf1, vf1, o[j], 0, 0, 0);
        }
    }

    // ---- epilogue: reduce l (quads via shfl, waves via LDS), store ----
#pragma unroll
    for (int qj = 0; qj < 4; ++qj) {
        float l = l_p[qj];
        l += __shfl_xor(l, 16);
        l += __shfl_xor(l, 32);
        if (quad == 0) lred[wave][qj*16 + l16] = l;
    }
    __syncthreads();
    if (tid < 64)
        linv[tid] = 1.0f / (lred[0][tid] + lred[1][tid] + lred[2][tid] + lred[3][tid]);
    __syncthreads();
#pragma unroll
    for (int r = 0; r < 4; ++r) {
        const int q = wave*16 + quad*4 + r;
        float inv = linv[q];
        u16* dst = attn_bf + (size_t)(b * SEQ + q0 + q) * DMODEL + h * HD;
#pragma unroll
        for (int j = 0; j < 4; ++j)
            dst[j*16 + l16] = f2bf(o[j][r] * inv);
    }
}

// ---------------------------------------------------------------------------
extern "C" void kernel_launch(void* const* d_in, const int* in_sizes, int n_in,
                              void* d_out, int out_size, void* d_ws, size_t ws_size,
                              hipStream_t stream)
{
    (void)in_sizes; (void)n_in; (void)out_size; (void)ws_size;
    const float* x      = (const float*)d_in[0];
    const float* qkv_w  = (const float*)d_in[1];
    const float* out_w  = (const float*)d_in[2];
    const float* bias_p = (const float*)d_in[3];
    const float* bias_a = (const float*)d_in[4];
    const float* freqs  = (const float*)d_in[5];
    float* out = (float*)d_out;

    // ws layout (bytes):
    //   [0, 24M)      qkv_bf [4096][3072] bf16   (attn_bf aliases [0,8M))
    //   [24M, 32M)    x_bf   [4096][1024] bf16   (Qb aliases after gemm1)
    //   [32M, 38M)    w1_bf  [3072][1024] bf16
    //   [38M, 40M)    w2_bf  [1024][1024] bf16
    //   [40M, 48M)    Kb     [2][16][2048][64] bf16
    //   [48M, 56M)    Vt     [2][16][64][2048] bf16
    //   [56M, +128K)  wtab   [16][2048] f32 (exp of bias)
    //   [+128K,+640K) cs_tab [2048][32][2] f32
    char* ws = (char*)d_ws;
    u16*   qkv_bf  = (u16*)ws;
    u16*   attn_bf = (u16*)ws;
    u16*   x_bf    = (u16*)(ws + 25165824);
    u16*   Qb      = x_bf;
    u16*   w1_bf   = (u16*)(ws + 33554432);
    u16*   w2_bf   = (u16*)(ws + 39845888);
    u16*   Kb      = (u16*)(ws + 41943040);
    u16*   Vt      = (u16*)(ws + 50331648);
    float* wtab    = (float*)(ws + 58720256);
    float* cs_tab  = (float*)(ws + 58720256 + 131072);

    const int na = ROWS*DMODEL, nb = NQKV*DMODEL, nc = DMODEL*DMODEL;
    f2bf3_kernel<<<dim3((na+nb+nc)/1024), 256, 0, stream>>>(x, na, qkv_w, nb, out_w, nc,
                                                            x_bf, w1_bf, w2_bf);
    rope_table_kernel<<<dim3(SEQ*32/256), 256, 0, stream>>>(freqs, cs_tab);
    wtab_kernel<<<dim3(NH*SEQ/256), 256, 0, stream>>>(bias_p, bias_a, wtab);

    gemm_bf16<true><<<dim3(ROWS/128, NQKV/128), 256, 0, stream>>>(x_bf, w1_bf, qkv_bf, ROWS, NQKV, DMODEL);
    qkv_convert<<<dim3(SEQ/64, NH, BATCH), 256, 0, stream>>>(qkv_bf, cs_tab, Qb, Kb, Vt);
    attn_mfma<<<dim3(SEQ/64, NH, BATCH), 256, 0, stream>>>(Qb, Kb, Vt, wtab, attn_bf);
    gemm_bf16<false><<<dim3(ROWS/128, DMODEL/128), 256, 0, stream>>>(attn_bf, w2_bf, out, ROWS, DMODEL, DMODEL);
}